// Round 2
// baseline (75.539 us; speedup 1.0000x reference)
//
#include <hip/hip_runtime.h>
#include <hip/hip_bf16.h>

// Problem constants (fixed by setup_inputs)
#define NG   256   // graphs
#define NPG  64    // nodes per graph
#define INF  128   // in features (K)
#define OUTF 128   // out features (N)
#define NH   16    // heads

typedef __attribute__((ext_vector_type(8))) short bf16x8;  // 8 bf16 = 4 VGPRs
typedef __attribute__((ext_vector_type(4))) float f32x4;   // MFMA accumulator

__device__ __forceinline__ ushort f2bf(float f) {
    union { float f; unsigned int i; } c; c.f = f;
    unsigned int r = c.i + 0x7fffu + ((c.i >> 16) & 1u);  // round-to-nearest-even
    return (ushort)(r >> 16);
}

// W[h][k][n] (fp32) -> Wt[h][n][k] (bf16), so MFMA B-fragments are
// k-contiguous 16B loads. grid: 16 heads * 4 (2x2 tiles of 64x64) = 64 blocks.
__global__ __launch_bounds__(256) void transpose_w_kernel(
    const float* __restrict__ W, ushort* __restrict__ Wt)
{
    int h  = blockIdx.x >> 2;
    int k0 = ((blockIdx.x >> 1) & 1) * 64;
    int n0 = (blockIdx.x & 1) * 64;
    int t  = (int)threadIdx.x;
    int n  = t & 63;   // output row within tile
    int kg = t >> 6;   // which 16-wide k chunk

    const float* src = W + h * (INF * OUTF) + (k0 + kg * 16) * OUTF + (n0 + n);
    ushort vals[16] __attribute__((aligned(16)));
#pragma unroll
    for (int j = 0; j < 16; ++j) vals[j] = f2bf(src[j * OUTF]);

    ushort* dst = Wt + h * (INF * OUTF) + (n0 + n) * INF + (k0 + kg * 16);
    *(uint4*)(dst)     = *(const uint4*)(&vals[0]);
    *(uint4*)(dst + 8) = *(const uint4*)(&vals[8]);
}

// One block per graph, 512 threads = 8 waves.
// Wave computes a 16-row x 64-col tile: rows (w&3)*16, cols (w>>2)*64.
// A-frag: X fp32 row-contiguous loads -> cvt bf16. B-frag: Wt bf16 16B loads.
__global__ __launch_bounds__(512) void mhl_gemm_kernel(
    const float*  __restrict__ X,     // [NG*NPG][INF] fp32
    const int*    __restrict__ head,  // [NG]
    const ushort* __restrict__ Wt,    // [NH][OUTF][INF] bf16 (transposed)
    const float*  __restrict__ bias,  // [NH][OUTF] fp32
    float*        __restrict__ Y)     // [NG*NPG][OUTF] fp32
{
    int g    = (int)blockIdx.x;
    int h    = head[g];
    int wave = (int)threadIdx.x >> 6;
    int lane = (int)threadIdx.x & 63;
    int quad = lane >> 4;
    int l16  = lane & 15;

    int mrow = (wave & 3) * 16;   // row tile within graph
    int ncol = (wave >> 2) * 64;  // column half

    // A fragments: A[m=l16][k=quad*8+j], kt tiles of 32 along K
    const float* Xg = X + (g * NPG + mrow + l16) * INF + quad * 8;
    bf16x8 a[4];
#pragma unroll
    for (int kt = 0; kt < 4; ++kt) {
        float v[8] __attribute__((aligned(16)));
        *(float4*)(&v[0]) = *(const float4*)(Xg + kt * 32);
        *(float4*)(&v[4]) = *(const float4*)(Xg + kt * 32 + 4);
#pragma unroll
        for (int j = 0; j < 8; ++j) a[kt][j] = (short)f2bf(v[j]);
    }

    const ushort* Wh = Wt + h * (INF * OUTF);
    f32x4 acc[4];
#pragma unroll
    for (int nt = 0; nt < 4; ++nt) acc[nt] = (f32x4){0.f, 0.f, 0.f, 0.f};

#pragma unroll
    for (int nt = 0; nt < 4; ++nt) {
        // B fragment: B[k=quad*8+j][n=l16] == Wt[n][k], k-contiguous
        const ushort* Wn = Wh + (ncol + nt * 16 + l16) * INF + quad * 8;
#pragma unroll
        for (int kt = 0; kt < 4; ++kt) {
            bf16x8 b = *(const bf16x8*)(Wn + kt * 32);
            acc[nt] = __builtin_amdgcn_mfma_f32_16x16x32_bf16(a[kt], b, acc[nt], 0, 0, 0);
        }
    }

    // Epilogue: C/D layout col=lane&15, row=quad*4+reg (m89-verified)
    float* Yg = Y + (g * NPG + mrow) * OUTF + ncol;
#pragma unroll
    for (int nt = 0; nt < 4; ++nt) {
        float bv = bias[h * OUTF + ncol + nt * 16 + l16];
#pragma unroll
        for (int r = 0; r < 4; ++r)
            Yg[(quad * 4 + r) * OUTF + nt * 16 + l16] = acc[nt][r] + bv;
    }
}

extern "C" void kernel_launch(void* const* d_in, const int* in_sizes, int n_in,
                              void* d_out, int out_size, void* d_ws, size_t ws_size,
                              hipStream_t stream) {
    // setup_inputs order: inputs, n_node, head, kernel, bias
    const float* X    = (const float*)d_in[0];
    const int*   head = (const int*)d_in[2];
    const float* W    = (const float*)d_in[3];
    const float* bias = (const float*)d_in[4];
    float*  Y  = (float*)d_out;
    ushort* Wt = (ushort*)d_ws;   // 16*128*128*2 = 512 KB scratch

    transpose_w_kernel<<<NH * 4, 256, 0, stream>>>(W, Wt);
    mhl_gemm_kernel<<<NG, 512, 0, stream>>>(X, head, Wt, bias, Y);
}

// Round 3
// 72.057 us; speedup vs baseline: 1.0483x; 1.0483x over previous
//
#include <hip/hip_runtime.h>
#include <hip/hip_bf16.h>

// Problem constants (fixed by setup_inputs)
#define NG   256   // graphs
#define NPG  64    // nodes per graph
#define INF  128   // in features (K)
#define OUTF 128   // out features (N)
#define NH   16    // heads

// LDS row stride for Wl[n][k] in bf16 units.
// 136 bf16 = 272 B = 68 dwords: rows stay 16B-aligned (ds_read_b128 ok) and
// the b128 B-fragment read pattern (start bank 4*(n+q) % 32) spreads
// 64 lanes x 4 dwords uniformly at 8 dwords/bank = the conflict-free minimum.
#define LDSK 136

typedef __attribute__((ext_vector_type(8))) short bf16x8;  // 8 bf16 = 4 VGPRs
typedef __attribute__((ext_vector_type(4))) float f32x4;   // MFMA accumulator

__device__ __forceinline__ ushort f2bf(float f) {
    union { float f; unsigned int i; } c; c.f = f;
    unsigned int r = c.i + 0x7fffu + ((c.i >> 16) & 1u);  // round-to-nearest-even
    return (ushort)(r >> 16);
}

// One block per graph, 512 threads = 8 waves.
// Phase 1: stage W[head[g]] (fp32 [k][n]) -> LDS Wl[n][k] bf16 (transposed).
// Phase 2: wave computes a 16-row x 64-col tile: rows (w&3)*16, cols (w>>2)*64.
//   A-frag: X fp32 row-contiguous float4 loads -> cvt bf16.
//   B-frag: ds_read_b128 from Wl (k-contiguous).
__global__ __launch_bounds__(512) void mhl_fused_kernel(
    const float* __restrict__ X,     // [NG*NPG][INF] fp32
    const int*   __restrict__ head,  // [NG]
    const float* __restrict__ W,     // [NH][INF][OUTF] fp32
    const float* __restrict__ bias,  // [NH][OUTF] fp32
    float*       __restrict__ Y)     // [NG*NPG][OUTF] fp32
{
    __shared__ ushort Wl[OUTF * LDSK];  // 128*136*2 = 34816 B

    int g = (int)blockIdx.x;
    int h = head[g];
    int t = (int)threadIdx.x;

    // ---- Phase 1: stage W[h] into LDS, transposed, bf16 ----
    // thread t: row k = t/4, cols (t%4)*32 .. +31  (coalesced float4 reads)
    {
        int k  = t >> 2;
        int c0 = (t & 3) * 32;
        const float* src = W + h * (INF * OUTF) + k * OUTF + c0;
#pragma unroll
        for (int j = 0; j < 32; j += 4) {
            float4 v = *(const float4*)(src + j);
            Wl[(c0 + j + 0) * LDSK + k] = f2bf(v.x);
            Wl[(c0 + j + 1) * LDSK + k] = f2bf(v.y);
            Wl[(c0 + j + 2) * LDSK + k] = f2bf(v.z);
            Wl[(c0 + j + 3) * LDSK + k] = f2bf(v.w);
        }
    }
    __syncthreads();

    // ---- Phase 2: MFMA GEMM ----
    int wave = t >> 6;
    int lane = t & 63;
    int quad = lane >> 4;
    int l16  = lane & 15;

    int mrow = (wave & 3) * 16;   // row tile within graph
    int ncol = (wave >> 2) * 64;  // column half

    // A fragments: A[m=l16][k=quad*8+j], kt tiles of 32 along K
    const float* Xg = X + (g * NPG + mrow + l16) * INF + quad * 8;
    bf16x8 a[4];
#pragma unroll
    for (int kt = 0; kt < 4; ++kt) {
        float v[8] __attribute__((aligned(16)));
        *(float4*)(&v[0]) = *(const float4*)(Xg + kt * 32);
        *(float4*)(&v[4]) = *(const float4*)(Xg + kt * 32 + 4);
#pragma unroll
        for (int j = 0; j < 8; ++j) a[kt][j] = (short)f2bf(v[j]);
    }

    f32x4 acc[4];
#pragma unroll
    for (int nt = 0; nt < 4; ++nt) acc[nt] = (f32x4){0.f, 0.f, 0.f, 0.f};

#pragma unroll
    for (int nt = 0; nt < 4; ++nt) {
        // B fragment: B[k=quad*8+j][n=l16] == Wl[n][k], k-contiguous in LDS
        const ushort* Wn = &Wl[(ncol + nt * 16 + l16) * LDSK + quad * 8];
#pragma unroll
        for (int kt = 0; kt < 4; ++kt) {
            bf16x8 b = *(const bf16x8*)(Wn + kt * 32);
            acc[nt] = __builtin_amdgcn_mfma_f32_16x16x32_bf16(a[kt], b, acc[nt], 0, 0, 0);
        }
    }

    // ---- Epilogue: C/D layout col=lane&15, row=quad*4+reg (m89-verified) ----
    float* Yg = Y + (g * NPG + mrow) * OUTF + ncol;
#pragma unroll
    for (int nt = 0; nt < 4; ++nt) {
        float bv = bias[h * OUTF + ncol + nt * 16 + l16];
#pragma unroll
        for (int r = 0; r < 4; ++r)
            Yg[(quad * 4 + r) * OUTF + nt * 16 + l16] = acc[nt][r] + bv;
    }
}

extern "C" void kernel_launch(void* const* d_in, const int* in_sizes, int n_in,
                              void* d_out, int out_size, void* d_ws, size_t ws_size,
                              hipStream_t stream) {
    // setup_inputs order: inputs, n_node, head, kernel, bias
    const float* X    = (const float*)d_in[0];
    const int*   head = (const int*)d_in[2];
    const float* W    = (const float*)d_in[3];
    const float* bias = (const float*)d_in[4];
    float* Y = (float*)d_out;

    mhl_fused_kernel<<<NG, 512, 0, stream>>>(X, head, W, bias, Y);
}